// Round 1
// baseline (15122.720 us; speedup 1.0000x reference)
//
#include <hip/hip_runtime.h>
#include <hip/hip_bf16.h>
#include <stdint.h>

// GRU-style recurrence, B=64 S=512 D=768 H=1024.
// Plan:
//  prep:  cast x->bf16; build Wcat_u (bf16 [3072,1024] = first-H cols of Wz|Wr|Wi);
//         transpose-cast Wm -> WmT bf16 [768,1024]; cast Wh; ccat[n] = W*u@bm + b*;
//         pack recurrent weights (W*[:,H:]) into per-block MFMA B-fragments.
//  fold:  Mcat[3072,768] = Wcat_u @ WmT^T            (NT bf16 MFMA GEMM)
//  big:   Gcat[32768,3072] = xbf @ Mcat^T + ccat     (NT bf16 MFMA GEMM, bf16 out)
//  h0:    hf[64,1024] = x[:,0,:] @ Whbf^T + bh       (same GEMM, f32 out, lda=S*D)
//  rec:   persistent kernel, 256 blocks = 4 groups(16 batch rows) x 64 blocks.
//         Block j: 32 zr-cols + 16 i-cols, weights resident in VGPRs.
//         2 phases/step, flag-array sync (agent-scope release/acquire).

#define B_  64
#define S_  512
#define D_  768
#define H_  1024

typedef __attribute__((ext_vector_type(8))) short short8;
typedef __attribute__((ext_vector_type(4))) float f32x4;

static __device__ __forceinline__ short f2bf(float f) {
  union { float f; uint32_t u; } v; v.f = f;
  uint32_t u = v.u;
  u += 0x7FFFu + ((u >> 16) & 1u);   // RNE
  return (short)(u >> 16);
}
static __device__ __forceinline__ float bf2f(short s) {
  union { uint32_t u; float f; } v; v.u = ((uint32_t)(uint16_t)s) << 16;
  return v.f;
}
static __device__ __forceinline__ void load_lds16(const void* g, void* l) {
  __builtin_amdgcn_global_load_lds((const __attribute__((address_space(1))) void*)g,
                                   (__attribute__((address_space(3))) void*)l, 16, 0, 0);
}

// ---------------- prep kernels ----------------

__global__ void cast_f32_bf16_kernel(const float* __restrict__ in, short* __restrict__ out, int n8) {
  int i = blockIdx.x * blockDim.x + threadIdx.x;
  int stride = gridDim.x * blockDim.x;
  for (; i < n8; i += stride) {
    const f32x4* p = (const f32x4*)(in + (size_t)i * 8);
    f32x4 a = p[0], b = p[1];
    short8 o;
    o[0] = f2bf(a[0]); o[1] = f2bf(a[1]); o[2] = f2bf(a[2]); o[3] = f2bf(a[3]);
    o[4] = f2bf(b[0]); o[5] = f2bf(b[1]); o[6] = f2bf(b[2]); o[7] = f2bf(b[3]);
    *(short8*)(out + (size_t)i * 8) = o;
  }
}

// Wcat_u bf16 [3072][1024]: rows 0..1023 = Wz[:, :1024], 1024..2047 = Wr[:, :1024], 2048.. = Wi[:, :1024]
__global__ void build_wcat_kernel(const float* __restrict__ Wz, const float* __restrict__ Wr,
                                  const float* __restrict__ Wi, short* __restrict__ out) {
  int idx = blockIdx.x * blockDim.x + threadIdx.x;   // 3072*128
  int n = idx >> 7;
  int k8 = (idx & 127) << 3;
  const float* src;
  if (n < 1024)       src = Wz + ((size_t)n << 11);
  else if (n < 2048)  src = Wr + ((size_t)(n - 1024) << 11);
  else                src = Wi + ((size_t)(n - 2048) << 11);
  const f32x4* p = (const f32x4*)(src + k8);
  f32x4 a = p[0], b = p[1];
  short8 o;
  o[0] = f2bf(a[0]); o[1] = f2bf(a[1]); o[2] = f2bf(a[2]); o[3] = f2bf(a[3]);
  o[4] = f2bf(b[0]); o[5] = f2bf(b[1]); o[6] = f2bf(b[2]); o[7] = f2bf(b[3]);
  *(short8*)(out + ((size_t)n << 10) + k8) = o;
}

// WmT bf16 [768][1024], WmT[d][u] = Wm[u][d]
__global__ void transpose_cast_kernel(const float* __restrict__ in, short* __restrict__ out) {
  __shared__ float tile[32][33];
  int x = (blockIdx.x << 5) + threadIdx.x;    // col of in (d), grid.x = 24
  int y0 = (blockIdx.y << 5);                 // row of in (u), grid.y = 32
#pragma unroll
  for (int i = threadIdx.y; i < 32; i += 8)
    tile[i][threadIdx.x] = in[(size_t)(y0 + i) * 768 + x];
  __syncthreads();
  int ox = (blockIdx.y << 5) + threadIdx.x;   // col of out (u)
  int oy0 = (blockIdx.x << 5);                // row of out (d)
#pragma unroll
  for (int i = threadIdx.y; i < 32; i += 8)
    out[(size_t)(oy0 + i) * 1024 + ox] = f2bf(tile[threadIdx.x][i]);
}

// ccat[n] = sum_k W*[n_local, k<1024] * bm[k] + b*[n_local], wave-per-row
__global__ void ccat_kernel(const float* __restrict__ Wz, const float* __restrict__ Wr,
                            const float* __restrict__ Wi, const float* __restrict__ bm,
                            const float* __restrict__ bz, const float* __restrict__ br,
                            const float* __restrict__ bi, float* __restrict__ ccat) {
  int w = (blockIdx.x * blockDim.x + threadIdx.x) >> 6;
  int lane = threadIdx.x & 63;
  if (w >= 3072) return;
  const float* src; const float* bsrc; int ln;
  if (w < 1024)      { src = Wz + ((size_t)w << 11);          bsrc = bz; ln = w; }
  else if (w < 2048) { src = Wr + ((size_t)(w - 1024) << 11); bsrc = br; ln = w - 1024; }
  else               { src = Wi + ((size_t)(w - 2048) << 11); bsrc = bi; ln = w - 2048; }
  float acc = 0.f;
  for (int k = lane; k < 1024; k += 64) acc += src[k] * bm[k];
  for (int off = 32; off > 0; off >>= 1) acc += __shfl_down(acc, off, 64);
  if (lane == 0) ccat[w] = acc + bsrc[ln];
}

// pack zr recurrent weights: layout [(j*4+w)*16+t][lane][8]
// lane: col = j*32 + (w&1)*16 + (lane&15); k = (w>>1)*512 + t*32 + (lane>>4)*8
__global__ void pack_zr_kernel(const float* __restrict__ Wz, const float* __restrict__ Wr,
                               short* __restrict__ out) {
  int idx = blockIdx.x * blockDim.x + threadIdx.x;   // 262144
  int lane = idx & 63;
  int t = (idx >> 6) & 15;
  int w = (idx >> 10) & 3;
  int j = idx >> 12;
  int col = j * 32 + (w & 1) * 16 + (lane & 15);
  int k = (w >> 1) * 512 + t * 32 + ((lane >> 4) << 3);
  const float* p = ((j < 32) ? (Wz + ((size_t)col << 11)) : (Wr + ((size_t)(col - 1024) << 11)))
                   + 1024 + k;
  short8 o;
#pragma unroll
  for (int e = 0; e < 8; ++e) o[e] = f2bf(p[e]);
  *(short8*)(out + ((size_t)idx << 3)) = o;
}

// pack i recurrent weights: layout [(j*4+w)*8+t][lane][8]
// lane: col = j*16 + (lane&15); k = w*256 + t*32 + (lane>>4)*8
__global__ void pack_i_kernel(const float* __restrict__ Wi, short* __restrict__ out) {
  int idx = blockIdx.x * blockDim.x + threadIdx.x;   // 131072
  int lane = idx & 63;
  int t = (idx >> 6) & 7;
  int w = (idx >> 9) & 3;
  int j = idx >> 11;
  int col = j * 16 + (lane & 15);
  int k = w * 256 + t * 32 + ((lane >> 4) << 3);
  const float* p = Wi + ((size_t)col << 11) + 1024 + k;
  short8 o;
#pragma unroll
  for (int e = 0; e < 8; ++e) o[e] = f2bf(p[e]);
  *(short8*)(out + ((size_t)idx << 3)) = o;
}

// ---------------- NT bf16 MFMA GEMM: C[M,N] = A[M,K] @ Bm[N,K]^T (+bias[col]) ----------------
// 128x128 tile, BK=64, 4 waves (2x2), m97-style 2-barrier loop, XOR-swizzled LDS.

template<bool OUT_F32>
__launch_bounds__(256, 2)
__global__ void gemm_nt_kernel(const short* __restrict__ A, long lda,
                               const short* __restrict__ Bm,
                               void* __restrict__ Cv, int ldc,
                               const float* __restrict__ bias,
                               int M, int N, int K) {
  __shared__ short ldsA[128 * 64];
  __shared__ short ldsB[128 * 64];
  const int tile_m = blockIdx.x << 7;
  const int tile_n = blockIdx.y << 7;
  const int tid = threadIdx.x;
  const int wave = tid >> 6;
  const int lane = tid & 63;
  const int wm = wave & 1;
  const int wn = wave >> 1;
  const int lrow = lane & 15;
  const int lgrp = lane >> 4;

  f32x4 acc[4][4];
#pragma unroll
  for (int a = 0; a < 4; ++a)
#pragma unroll
    for (int b = 0; b < 4; ++b) acc[a][b] = (f32x4){0.f, 0.f, 0.f, 0.f};

  for (int kt = 0; kt < K; kt += 64) {
    __syncthreads();
#pragma unroll
    for (int c = 0; c < 4; ++c) {
      int o = ((wave * 4 + c) << 10) + (lane << 4);
      int row = o >> 7;
      int cb = (o & 127) ^ ((row & 7) << 4);   // pre-swizzled source (rule 21)
      int grow = tile_m + row; if (grow >= M) grow = M - 1;
      load_lds16(A + (size_t)grow * lda + kt + (cb >> 1),
                 (char*)ldsA + ((wave * 4 + c) << 10));
      int gcol = tile_n + row;
      load_lds16(Bm + (size_t)gcol * K + kt + (cb >> 1),
                 (char*)ldsB + ((wave * 4 + c) << 10));
    }
    __syncthreads();
#pragma unroll
    for (int kk = 0; kk < 2; ++kk) {
      short8 af[4], bfr[4];
      int kb = (kk << 6) + (lgrp << 4);
#pragma unroll
      for (int a = 0; a < 4; ++a) {
        int r = (wm << 6) + (a << 4) + lrow;
        af[a] = *(const short8*)((const char*)ldsA + (r << 7) + (kb ^ ((r & 7) << 4)));
        int rn = (wn << 6) + (a << 4) + lrow;
        bfr[a] = *(const short8*)((const char*)ldsB + (rn << 7) + (kb ^ ((rn & 7) << 4)));
      }
#pragma unroll
      for (int a = 0; a < 4; ++a)
#pragma unroll
        for (int b = 0; b < 4; ++b)
          acc[a][b] = __builtin_amdgcn_mfma_f32_16x16x32_bf16(af[a], bfr[b], acc[a][b], 0, 0, 0);
    }
  }
#pragma unroll
  for (int a = 0; a < 4; ++a)
#pragma unroll
    for (int b = 0; b < 4; ++b)
#pragma unroll
      for (int q = 0; q < 4; ++q) {
        int r = tile_m + (wm << 6) + (a << 4) + lgrp * 4 + q;   // measured C layout (m89)
        int cc = tile_n + (wn << 6) + (b << 4) + lrow;
        if (r < M) {
          float v = acc[a][b][q];
          if (bias) v += bias[cc];
          if (OUT_F32) ((float*)Cv)[(size_t)r * ldc + cc] = v;
          else         ((short*)Cv)[(size_t)r * ldc + cc] = f2bf(v);
        }
      }
}

// ---------------- persistent recurrence ----------------
// 256 blocks: g = blk>>6 (batch group of 16 rows), j = blk&63.
// phase1: block j computes zr-cols 32j..32j+31 (j<32: z, j>=32: r) for its group.
// phase2: block j computes i-cols 16j..16j+15, h update.

__launch_bounds__(256, 1)
__global__ void recurrence_kernel(const short* __restrict__ pzr,
                                  const short* __restrict__ pii,
                                  const short* __restrict__ Gcat,
                                  float* __restrict__ hf,
                                  short* __restrict__ hbf,
                                  short* __restrict__ rhbf,
                                  float* __restrict__ zbuf,
                                  uint32_t* __restrict__ flags,
                                  float* __restrict__ out) {
  __shared__ short stage[16 * 1024];    // 32 KB: h or r*h tile, swizzled
  __shared__ float red[3][256];
  const int blk = blockIdx.x;
  const int g = blk >> 6;
  const int j = blk & 63;
  const int tid = threadIdx.x;
  const int wave = tid >> 6;
  const int lane = tid & 63;
  const int nw = wave & 1;
  const int kw = wave >> 1;
  const int m0 = g << 4;
  const int lrow = lane & 15;
  const int lgrp = lane >> 4;

  // resident weight fragments
  short8 wzr[16];
  const short8* pz8 = (const short8*)pzr;
#pragma unroll
  for (int t = 0; t < 16; ++t) wzr[t] = pz8[(size_t)((j * 4 + wave) * 16 + t) * 64 + lane];
  short8 wii[8];
  const short8* pi8 = (const short8*)pii;
#pragma unroll
  for (int t = 0; t < 8; ++t) wii[t] = pi8[(size_t)((j * 4 + wave) * 8 + t) * 64 + lane];

  uint32_t* flag1 = flags + (g * 2 + 0) * 64;
  uint32_t* flag2 = flags + (g * 2 + 1) * 64;
  const bool is_r = (j >= 32);
  const int zr_col = j * 32 + nw * 16 + lrow;   // 0..2047 (epilogue waves kw==0)
  const int icol = j * 16 + lrow;

  for (int t = 0; t < S_; ++t) {
    // ---- phase 1: wait h ready ----
    if (t > 0 && tid < 64) {
      for (;;) {
        uint32_t v = __hip_atomic_load(flag1 /*dummy*/ , __ATOMIC_RELAXED, __HIP_MEMORY_SCOPE_AGENT); (void)v;
        uint32_t f = __hip_atomic_load(flag2 + tid, __ATOMIC_ACQUIRE, __HIP_MEMORY_SCOPE_AGENT);
        if (__all((int)(f >= (uint32_t)t))) break;
        __builtin_amdgcn_s_sleep(2);
      }
    }
    __syncthreads();
    float gpre[4];
    if (kw == 0) {
#pragma unroll
      for (int jj = 0; jj < 4; ++jj) {
        int b = m0 + lgrp * 4 + jj;
        gpre[jj] = bf2f(Gcat[((size_t)b * S_ + t) * 3072 + zr_col]);
      }
    }
    // stage h (bf16, swizzled)
#pragma unroll
    for (int it = 0; it < 8; ++it) {
      int o = ((it * 4 + wave) << 10) + (lane << 4);
      int row = o >> 11;
      int cb = (o & 2047) ^ ((row & 7) << 4);
      load_lds16(hbf + ((size_t)(m0 + row) << 10) + (cb >> 1),
                 (char*)stage + ((it * 4 + wave) << 10));
    }
    __syncthreads();
    f32x4 acc = (f32x4){0.f, 0.f, 0.f, 0.f};
#pragma unroll
    for (int tt = 0; tt < 16; ++tt) {
      int kbyte = (kw << 10) + (tt << 6) + (lgrp << 4);
      const short8 av = *(const short8*)((const char*)stage + (lrow << 11) + (kbyte ^ ((lrow & 7) << 4)));
      acc = __builtin_amdgcn_mfma_f32_16x16x32_bf16(av, wzr[tt], acc, 0, 0, 0);
    }
    if (kw == 1) {
#pragma unroll
      for (int jj = 0; jj < 4; ++jj) red[nw][(lgrp * 4 + jj) * 16 + lrow] = acc[jj];
    }
    __syncthreads();
    if (kw == 0) {
#pragma unroll
      for (int jj = 0; jj < 4; ++jj) {
        float pre = acc[jj] + red[nw][(lgrp * 4 + jj) * 16 + lrow] + gpre[jj];
        pre = fminf(fmaxf(pre, -30.f), 30.f);
        float sg = 1.f / (1.f + __expf(-pre));
        int b = m0 + lgrp * 4 + jj;
        if (!is_r) {
          zbuf[((size_t)b << 10) + zr_col] = sg;
        } else {
          int hc = zr_col - 1024;
          float hv = hf[((size_t)b << 10) + hc];
          rhbf[((size_t)b << 10) + hc] = f2bf(sg * hv);
        }
      }
    }
    __syncthreads();
    if (tid == 0) __hip_atomic_store(flag1 + j, (uint32_t)(t + 1), __ATOMIC_RELEASE, __HIP_MEMORY_SCOPE_AGENT);

    // ---- phase 2: wait all z,r ready ----
    if (tid < 64) {
      for (;;) {
        uint32_t f = __hip_atomic_load(flag1 + tid, __ATOMIC_ACQUIRE, __HIP_MEMORY_SCOPE_AGENT);
        if (__all((int)(f >= (uint32_t)(t + 1)))) break;
        __builtin_amdgcn_s_sleep(2);
      }
    }
    __syncthreads();
    float gpre2[4], zv[4], hold[4];
    if (wave == 0) {
#pragma unroll
      for (int jj = 0; jj < 4; ++jj) {
        int b = m0 + lgrp * 4 + jj;
        gpre2[jj] = bf2f(Gcat[((size_t)b * S_ + t) * 3072 + 2048 + icol]);
        zv[jj] = zbuf[((size_t)b << 10) + icol];
        hold[jj] = hf[((size_t)b << 10) + icol];
      }
    }
#pragma unroll
    for (int it = 0; it < 8; ++it) {
      int o = ((it * 4 + wave) << 10) + (lane << 4);
      int row = o >> 11;
      int cb = (o & 2047) ^ ((row & 7) << 4);
      load_lds16(rhbf + ((size_t)(m0 + row) << 10) + (cb >> 1),
                 (char*)stage + ((it * 4 + wave) << 10));
    }
    __syncthreads();
    f32x4 acc2 = (f32x4){0.f, 0.f, 0.f, 0.f};
#pragma unroll
    for (int tt = 0; tt < 8; ++tt) {
      int kbyte = (wave << 9) + (tt << 6) + (lgrp << 4);
      const short8 av = *(const short8*)((const char*)stage + (lrow << 11) + (kbyte ^ ((lrow & 7) << 4)));
      acc2 = __builtin_amdgcn_mfma_f32_16x16x32_bf16(av, wii[tt], acc2, 0, 0, 0);
    }
    if (wave != 0) {
#pragma unroll
      for (int jj = 0; jj < 4; ++jj) red[wave - 1][(lgrp * 4 + jj) * 16 + lrow] = acc2[jj];
    }
    __syncthreads();
    if (wave == 0) {
#pragma unroll
      for (int jj = 0; jj < 4; ++jj) {
        int idx = (lgrp * 4 + jj) * 16 + lrow;
        float pre = acc2[jj] + red[0][idx] + red[1][idx] + red[2][idx] + gpre2[jj];
        pre = fminf(fmaxf(pre, -30.f), 30.f);
        float e2 = __expf(2.f * pre);
        float hp = (e2 - 1.f) / (e2 + 1.f);
        float hn = (1.f - zv[jj]) * hold[jj] + zv[jj] * hp;
        int b = m0 + lgrp * 4 + jj;
        hf[((size_t)b << 10) + icol] = hn;
        hbf[((size_t)b << 10) + icol] = f2bf(hn);
        if (t == S_ - 1) out[((size_t)b << 10) + icol] = hn;
      }
    }
    __syncthreads();
    if (tid == 0) __hip_atomic_store(flag2 + j, (uint32_t)(t + 1), __ATOMIC_RELEASE, __HIP_MEMORY_SCOPE_AGENT);
  }
}

// ---------------- launch ----------------

extern "C" void kernel_launch(void* const* d_in, const int* in_sizes, int n_in,
                              void* d_out, int out_size, void* d_ws, size_t ws_size,
                              hipStream_t stream) {
  const float* x  = (const float*)d_in[0];
  const float* Wm = (const float*)d_in[1];
  const float* bm = (const float*)d_in[2];
  const float* Wh = (const float*)d_in[3];
  const float* bh = (const float*)d_in[4];
  const float* Wz = (const float*)d_in[5];
  const float* bz = (const float*)d_in[6];
  const float* Wr = (const float*)d_in[7];
  const float* br = (const float*)d_in[8];
  const float* Wi = (const float*)d_in[9];
  const float* bi = (const float*)d_in[10];

  char* ws = (char*)d_ws;
  size_t off = 0;
  auto alloc = [&](size_t bytes) -> void* {
    void* p = ws + off; off += (bytes + 255) & ~(size_t)255; return p;
  };
  short* xbf   = (short*)alloc((size_t)B_ * S_ * D_ * 2);        // 50.3 MB
  short* Gcat  = (short*)alloc((size_t)B_ * S_ * 3072 * 2);      // 201.3 MB
  short* Mcat  = (short*)alloc((size_t)3072 * 768 * 2);
  short* Wcat  = (short*)alloc((size_t)3072 * 1024 * 2);
  short* WmT   = (short*)alloc((size_t)768 * 1024 * 2);
  short* Whbf  = (short*)alloc((size_t)1024 * 768 * 2);
  short* pzr   = (short*)alloc((size_t)4194304);
  short* pii   = (short*)alloc((size_t)2097152);
  float* ccat  = (float*)alloc(3072 * 4);
  float* hf    = (float*)alloc(65536 * 4);
  short* hbf   = (short*)alloc(65536 * 2);
  short* rhbf  = (short*)alloc(65536 * 2);
  float* zbuf  = (float*)alloc(65536 * 4);
  uint32_t* flags = (uint32_t*)alloc(2048);
  if (off > ws_size) return;   // workspace too small (~273 MB needed)

  hipMemsetAsync(flags, 0, 2048, stream);
  cast_f32_bf16_kernel<<<2048, 256, 0, stream>>>(x, xbf, (B_ * S_ * D_) / 8);
  cast_f32_bf16_kernel<<<384, 256, 0, stream>>>(Wh, Whbf, (1024 * 768) / 8);
  build_wcat_kernel<<<1536, 256, 0, stream>>>(Wz, Wr, Wi, Wcat);
  transpose_cast_kernel<<<dim3(24, 32), dim3(32, 8), 0, stream>>>(Wm, WmT);
  ccat_kernel<<<768, 256, 0, stream>>>(Wz, Wr, Wi, bm, bz, br, bi, ccat);
  pack_zr_kernel<<<1024, 256, 0, stream>>>(Wz, Wr, pzr);
  pack_i_kernel<<<512, 256, 0, stream>>>(Wi, pii);

  // Mcat[3072,768] = Wcat[3072,1024] @ WmT[768,1024]^T
  gemm_nt_kernel<false><<<dim3(24, 6), 256, 0, stream>>>(Wcat, 1024, WmT, Mcat, 768,
                                                         nullptr, 3072, 768, 1024);
  // Gcat[32768,3072] = xbf[32768,768] @ Mcat[3072,768]^T + ccat
  gemm_nt_kernel<false><<<dim3(256, 24), 256, 0, stream>>>(xbf, 768, Mcat, Gcat, 3072,
                                                           ccat, 32768, 3072, 768);
  // hf[64,1024] = x[:,0,:] @ Whbf[1024,768]^T + bh   (A row stride = S*D)
  gemm_nt_kernel<true><<<dim3(1, 8), 256, 0, stream>>>(xbf, (long)S_ * D_, Whbf, hf, 1024,
                                                       bh, 64, 1024, 768);
  cast_f32_bf16_kernel<<<32, 256, 0, stream>>>(hf, hbf, 65536 / 8);

  recurrence_kernel<<<256, 256, 0, stream>>>(pzr, pii, Gcat, hf, hbf, rhbf, zbuf, flags,
                                             (float*)d_out);
}

// Round 2
// 7229.047 us; speedup vs baseline: 2.0919x; 2.0919x over previous
//
#include <hip/hip_runtime.h>
#include <hip/hip_bf16.h>
#include <stdint.h>

// GRU-style recurrence, B=64 S=512 D=768 H=1024.
//  prep:  cast x->bf16; Wcat_u bf16 [3072,1024]; WmT bf16; Wh bf16; ccat = W*_u@bm + b*;
//         pack recurrent weights (W*[:,1024:]) into per-block MFMA B-fragments (r,z,i).
//  fold:  Mcat[3072,768] = Wcat_u @ WmT^T           (NT bf16 MFMA GEMM)
//  big:   Gcat[32768,3072] = xbf @ Mcat^T + ccat    (NT bf16 MFMA GEMM, bf16 out)
//  h0:    hf[64,1024] = x[:,0,:] @ Whbf^T + bh
//  rec:   persistent, 256 blocks = 4 groups(16 rows) x 64 col-blocks(16 cols each).
//         Sync via monotonic flag counters (relaxed agent atomic_add) + sc0sc1 polls;
//         ALL cross-block data (h, r*h) moves through sc0 sc1 loads/stores (coherence
//         point = Infinity Cache) -> no buffer_inv/wbl2 cache-maintenance storms.

#define B_  64
#define S_  512
#define D_  768
#define H_  1024

typedef __attribute__((ext_vector_type(8))) short short8;
typedef __attribute__((ext_vector_type(4))) float f32x4;

static __device__ __forceinline__ short f2bf(float f) {
  union { float f; uint32_t u; } v; v.f = f;
  uint32_t u = v.u;
  u += 0x7FFFu + ((u >> 16) & 1u);   // RNE
  return (short)(u >> 16);
}
static __device__ __forceinline__ float bf2f(short s) {
  union { uint32_t u; float f; } v; v.u = ((uint32_t)(uint16_t)s) << 16;
  return v.f;
}
static __device__ __forceinline__ void load_lds16(const void* g, void* l) {
  __builtin_amdgcn_global_load_lds((const __attribute__((address_space(1))) void*)g,
                                   (__attribute__((address_space(3))) void*)l, 16, 0, 0);
}

// ---- fine-grained coherent (cross-XCD) accesses: sc0 sc1 = serialize at L3 ----
static __device__ __forceinline__ short8 load_frag_sys(const short* p) {
  short8 v;
  asm volatile("global_load_dwordx4 %0, %1, off sc0 sc1" : "=v"(v) : "v"(p));
  return v;
}
static __device__ __forceinline__ void store_bf16_sys(short* p, uint32_t v) {
  asm volatile("global_store_short %0, %1, off sc0 sc1" :: "v"(p), "v"(v) : "memory");
}
static __device__ __forceinline__ void wait_vm0() {
  asm volatile("s_waitcnt vmcnt(0)" ::: "memory");
  __builtin_amdgcn_sched_barrier(0);   // rule 18: keep consumers below the drain
}
static __device__ __forceinline__ void poll_ge(const uint32_t* p, uint32_t target) {
  uint32_t v;
  do {
    asm volatile("global_load_dword %0, %1, off sc0 sc1\n\ts_waitcnt vmcnt(0)"
                 : "=v"(v) : "v"(p) : "memory");
  } while (v < target);
}

// ---------------- prep kernels ----------------

__global__ void cast_f32_bf16_kernel(const float* __restrict__ in, short* __restrict__ out, int n8) {
  int i = blockIdx.x * blockDim.x + threadIdx.x;
  int stride = gridDim.x * blockDim.x;
  for (; i < n8; i += stride) {
    const f32x4* p = (const f32x4*)(in + (size_t)i * 8);
    f32x4 a = p[0], b = p[1];
    short8 o;
    o[0] = f2bf(a[0]); o[1] = f2bf(a[1]); o[2] = f2bf(a[2]); o[3] = f2bf(a[3]);
    o[4] = f2bf(b[0]); o[5] = f2bf(b[1]); o[6] = f2bf(b[2]); o[7] = f2bf(b[3]);
    *(short8*)(out + (size_t)i * 8) = o;
  }
}

// Wcat_u bf16 [3072][1024]: rows 0..1023 = Wz[:, :1024], then Wr, then Wi
__global__ void build_wcat_kernel(const float* __restrict__ Wz, const float* __restrict__ Wr,
                                  const float* __restrict__ Wi, short* __restrict__ out) {
  int idx = blockIdx.x * blockDim.x + threadIdx.x;   // 3072*128
  int n = idx >> 7;
  int k8 = (idx & 127) << 3;
  const float* src;
  if (n < 1024)       src = Wz + ((size_t)n << 11);
  else if (n < 2048)  src = Wr + ((size_t)(n - 1024) << 11);
  else                src = Wi + ((size_t)(n - 2048) << 11);
  const f32x4* p = (const f32x4*)(src + k8);
  f32x4 a = p[0], b = p[1];
  short8 o;
  o[0] = f2bf(a[0]); o[1] = f2bf(a[1]); o[2] = f2bf(a[2]); o[3] = f2bf(a[3]);
  o[4] = f2bf(b[0]); o[5] = f2bf(b[1]); o[6] = f2bf(b[2]); o[7] = f2bf(b[3]);
  *(short8*)(out + ((size_t)n << 10) + k8) = o;
}

// WmT bf16 [768][1024], WmT[d][u] = Wm[u][d]
__global__ void transpose_cast_kernel(const float* __restrict__ in, short* __restrict__ out) {
  __shared__ float tile[32][33];
  int x = (blockIdx.x << 5) + threadIdx.x;    // d, grid.x = 24
  int y0 = (blockIdx.y << 5);                 // u, grid.y = 32
#pragma unroll
  for (int i = threadIdx.y; i < 32; i += 8)
    tile[i][threadIdx.x] = in[(size_t)(y0 + i) * 768 + x];
  __syncthreads();
  int ox = (blockIdx.y << 5) + threadIdx.x;
  int oy0 = (blockIdx.x << 5);
#pragma unroll
  for (int i = threadIdx.y; i < 32; i += 8)
    out[(size_t)(oy0 + i) * 1024 + ox] = f2bf(tile[threadIdx.x][i]);
}

// ccat[n] = sum_k W*[n_local, k<1024] * bm[k] + b*[n_local]
__global__ void ccat_kernel(const float* __restrict__ Wz, const float* __restrict__ Wr,
                            const float* __restrict__ Wi, const float* __restrict__ bm,
                            const float* __restrict__ bz, const float* __restrict__ br,
                            const float* __restrict__ bi, float* __restrict__ ccat) {
  int w = (blockIdx.x * blockDim.x + threadIdx.x) >> 6;
  int lane = threadIdx.x & 63;
  if (w >= 3072) return;
  const float* src; const float* bsrc; int ln;
  if (w < 1024)      { src = Wz + ((size_t)w << 11);          bsrc = bz; ln = w; }
  else if (w < 2048) { src = Wr + ((size_t)(w - 1024) << 11); bsrc = br; ln = w - 1024; }
  else               { src = Wi + ((size_t)(w - 2048) << 11); bsrc = bi; ln = w - 2048; }
  float acc = 0.f;
  for (int k = lane; k < 1024; k += 64) acc += src[k] * bm[k];
  for (int off = 32; off > 0; off >>= 1) acc += __shfl_down(acc, off, 64);
  if (lane == 0) ccat[w] = acc + bsrc[ln];
}

// pack recurrent weights: idx = (((m*64 + j)*4 + w)*8 + t8)*64 + lane, m: 0=r 1=z 2=i
// value = W_m[16j + (lane&15)][1024 + 256w + 32*t8 + 8*(lane>>4) + e]
__global__ void pack_w_kernel(const float* __restrict__ Wz, const float* __restrict__ Wr,
                              const float* __restrict__ Wi, short* __restrict__ out) {
  int idx = blockIdx.x * blockDim.x + threadIdx.x;   // 393216
  int lane = idx & 63;
  int t8 = (idx >> 6) & 7;
  int w = (idx >> 9) & 3;
  int j = (idx >> 11) & 63;
  int m = idx >> 17;
  int colv = (j << 4) + (lane & 15);
  int k = 1024 + (w << 8) + (t8 << 5) + ((lane >> 4) << 3);
  const float* W = (m == 0) ? Wr : (m == 1) ? Wz : Wi;
  const float* p = W + ((size_t)colv << 11) + k;
  short8 o;
#pragma unroll
  for (int e = 0; e < 8; ++e) o[e] = f2bf(p[e]);
  *(short8*)(out + ((size_t)idx << 3)) = o;
}

// ---------------- NT bf16 MFMA GEMM: C[M,N] = A[M,K] @ Bm[N,K]^T (+bias[col]) ----------------

template<bool OUT_F32>
__launch_bounds__(256, 2)
__global__ void gemm_nt_kernel(const short* __restrict__ A, long lda,
                               const short* __restrict__ Bm,
                               void* __restrict__ Cv, int ldc,
                               const float* __restrict__ bias,
                               int M, int N, int K) {
  __shared__ short ldsA[128 * 64];
  __shared__ short ldsB[128 * 64];
  const int tile_m = blockIdx.x << 7;
  const int tile_n = blockIdx.y << 7;
  const int tid = threadIdx.x;
  const int wave = tid >> 6;
  const int lane = tid & 63;
  const int wm = wave & 1;
  const int wn = wave >> 1;
  const int lrow = lane & 15;
  const int lgrp = lane >> 4;

  f32x4 acc[4][4];
#pragma unroll
  for (int a = 0; a < 4; ++a)
#pragma unroll
    for (int b = 0; b < 4; ++b) acc[a][b] = (f32x4){0.f, 0.f, 0.f, 0.f};

  for (int kt = 0; kt < K; kt += 64) {
    __syncthreads();
#pragma unroll
    for (int c = 0; c < 4; ++c) {
      int o = ((wave * 4 + c) << 10) + (lane << 4);
      int row = o >> 7;
      int cb = (o & 127) ^ ((row & 7) << 4);   // pre-swizzled source (rule 21)
      int grow = tile_m + row; if (grow >= M) grow = M - 1;
      load_lds16(A + (size_t)grow * lda + kt + (cb >> 1),
                 (char*)ldsA + ((wave * 4 + c) << 10));
      int gcol = tile_n + row;
      load_lds16(Bm + (size_t)gcol * K + kt + (cb >> 1),
                 (char*)ldsB + ((wave * 4 + c) << 10));
    }
    __syncthreads();
#pragma unroll
    for (int kk = 0; kk < 2; ++kk) {
      short8 af[4], bfr[4];
      int kb = (kk << 6) + (lgrp << 4);
#pragma unroll
      for (int a = 0; a < 4; ++a) {
        int r = (wm << 6) + (a << 4) + lrow;
        af[a] = *(const short8*)((const char*)ldsA + (r << 7) + (kb ^ ((r & 7) << 4)));
        int rn = (wn << 6) + (a << 4) + lrow;
        bfr[a] = *(const short8*)((const char*)ldsB + (rn << 7) + (kb ^ ((rn & 7) << 4)));
      }
#pragma unroll
      for (int a = 0; a < 4; ++a)
#pragma unroll
        for (int b = 0; b < 4; ++b)
          acc[a][b] = __builtin_amdgcn_mfma_f32_16x16x32_bf16(af[a], bfr[b], acc[a][b], 0, 0, 0);
    }
  }
#pragma unroll
  for (int a = 0; a < 4; ++a)
#pragma unroll
    for (int b = 0; b < 4; ++b)
#pragma unroll
      for (int q = 0; q < 4; ++q) {
        int r = tile_m + (wm << 6) + (a << 4) + lgrp * 4 + q;   // m89 C layout
        int cc = tile_n + (wn << 6) + (b << 4) + lrow;
        if (r < M) {
          float v = acc[a][b][q];
          if (bias) v += bias[cc];
          if (OUT_F32) ((float*)Cv)[(size_t)r * ldc + cc] = v;
          else         ((short*)Cv)[(size_t)r * ldc + cc] = f2bf(v);
        }
      }
}

// ---------------- persistent recurrence ----------------
// 256 blocks: g = blk>>6 (16 batch rows), j = blk&63 (cols 16j..16j+16 of ALL gates).
// Per step: [poll hready] -> coherent h-frag loads -> r,z GEMMs (z result stays in regs)
//           -> reduce -> wave0: r=sig, store r*h coherent, flagA++ ->
//           [poll flagA] -> coherent rh-frag loads -> i GEMM -> reduce ->
//           wave0: h' = tanh, h_new, store h coherent, flagB++.
// h_old f32 (own 16 cols) lives in wave0 registers across all 512 steps.

__launch_bounds__(256, 1)
__global__ void recurrence_kernel(const short* __restrict__ pk,
                                  const short* __restrict__ Gcat,
                                  const float* __restrict__ hf,
                                  short* __restrict__ hbf,
                                  short* __restrict__ rhbf,
                                  uint32_t* __restrict__ flags,
                                  float* __restrict__ out) {
  __shared__ float red[3][3][256];    // [matrix r/z/i][wave-1][lane*4+q]
  const int blk = blockIdx.x;
  const int g = blk >> 6;
  const int j = blk & 63;
  const int tid = threadIdx.x;
  const int wave = tid >> 6;
  const int lane = tid & 63;
  const int lrow = lane & 15;
  const int lgrp = lane >> 4;
  const int m0 = g << 4;

  // resident weights: per wave k-quarter, 8 frags per matrix
  short8 wr[8], wz[8], wi[8];
  {
    const short8* p8 = (const short8*)pk;
    size_t base = ((size_t)j * 4 + wave) * 8;
#pragma unroll
    for (int t8 = 0; t8 < 8; ++t8) wr[t8] = p8[(base + t8) * 64 + lane];
#pragma unroll
    for (int t8 = 0; t8 < 8; ++t8) wz[t8] = p8[((size_t)2048 + base + t8) * 64 + lane];
#pragma unroll
    for (int t8 = 0; t8 < 8; ++t8) wi[t8] = p8[((size_t)4096 + base + t8) * 64 + lane];
  }

  uint32_t* flagA = flags + g * 32;
  uint32_t* flagB = flags + g * 32 + 16;

  const int col = (j << 4) + lrow;                   // C column (0..1023)
  float hold[4];
  if (wave == 0) {
#pragma unroll
    for (int q = 0; q < 4; ++q)
      hold[q] = hf[((size_t)(m0 + lgrp * 4 + q) << 10) + col];
  }

  const short* hrow  = hbf  + ((size_t)(m0 + lrow) << 10);   // A row = lane&15
  const short* rhrow = rhbf + ((size_t)(m0 + lrow) << 10);
  const int kq = wave << 8;

  for (int t = 0; t < S_; ++t) {
    // prefetch Gcat precomputed gate inputs (normal cached loads; overlap the polls)
    float gr[4], gz[4], gi[4];
    if (wave == 0) {
#pragma unroll
      for (int q = 0; q < 4; ++q) {
        size_t rbase = ((size_t)(m0 + lgrp * 4 + q) * S_ + t) * 3072;
        gz[q] = bf2f(Gcat[rbase + col]);
        gr[q] = bf2f(Gcat[rbase + 1024 + col]);
        gi[q] = bf2f(Gcat[rbase + 2048 + col]);
      }
    }
    if (t > 0) poll_ge(flagB, (uint32_t)(64 * t));
    // h fragments (coherent), feed BOTH r and z GEMMs
    short8 hfrag[8];
#pragma unroll
    for (int t8 = 0; t8 < 8; ++t8)
      hfrag[t8] = load_frag_sys(hrow + kq + (t8 << 5) + (lgrp << 3));
    wait_vm0();
    f32x4 accr = (f32x4){0.f,0.f,0.f,0.f}, accz = (f32x4){0.f,0.f,0.f,0.f};
#pragma unroll
    for (int t8 = 0; t8 < 8; ++t8) {
      accr = __builtin_amdgcn_mfma_f32_16x16x32_bf16(hfrag[t8], wr[t8], accr, 0, 0, 0);
      accz = __builtin_amdgcn_mfma_f32_16x16x32_bf16(hfrag[t8], wz[t8], accz, 0, 0, 0);
    }
    if (wave != 0) {
#pragma unroll
      for (int q = 0; q < 4; ++q) {
        red[0][wave - 1][lane * 4 + q] = accr[q];
        red[1][wave - 1][lane * 4 + q] = accz[q];
      }
    }
    __syncthreads();                                  // barrier 1
    f32x4 zt = (f32x4){0.f,0.f,0.f,0.f};
    if (wave == 0) {
#pragma unroll
      for (int q = 0; q < 4; ++q) {
        int li = lane * 4 + q;
        float sr = accr[q] + red[0][0][li] + red[0][1][li] + red[0][2][li] + gr[q];
        float sz = accz[q] + red[1][0][li] + red[1][1][li] + red[1][2][li] + gz[q];
        sr = fminf(fmaxf(sr, -30.f), 30.f);
        sz = fminf(fmaxf(sz, -30.f), 30.f);
        float rv = 1.f / (1.f + __expf(-sr));
        zt[q] = 1.f / (1.f + __expf(-sz));
        store_bf16_sys(rhbf + ((size_t)(m0 + lgrp * 4 + q) << 10) + col,
                       (uint32_t)(uint16_t)f2bf(rv * hold[q]));
      }
      wait_vm0();
      if (tid == 0)
        __hip_atomic_fetch_add(flagA, 1u, __ATOMIC_RELAXED, __HIP_MEMORY_SCOPE_AGENT);
    }
    poll_ge(flagA, (uint32_t)(64 * (t + 1)));
    short8 rhfrag[8];
#pragma unroll
    for (int t8 = 0; t8 < 8; ++t8)
      rhfrag[t8] = load_frag_sys(rhrow + kq + (t8 << 5) + (lgrp << 3));
    wait_vm0();
    f32x4 acci = (f32x4){0.f,0.f,0.f,0.f};
#pragma unroll
    for (int t8 = 0; t8 < 8; ++t8)
      acci = __builtin_amdgcn_mfma_f32_16x16x32_bf16(rhfrag[t8], wi[t8], acci, 0, 0, 0);
    if (wave != 0) {
#pragma unroll
      for (int q = 0; q < 4; ++q) red[2][wave - 1][lane * 4 + q] = acci[q];
    }
    __syncthreads();                                  // barrier 2
    if (wave == 0) {
#pragma unroll
      for (int q = 0; q < 4; ++q) {
        int li = lane * 4 + q;
        float si = acci[q] + red[2][0][li] + red[2][1][li] + red[2][2][li] + gi[q];
        si = fminf(fmaxf(si, -30.f), 30.f);
        float e2 = __expf(2.f * si);
        float hp = (e2 - 1.f) / (e2 + 1.f);
        float hn = (1.f - zt[q]) * hold[q] + zt[q] * hp;
        hold[q] = hn;
        store_bf16_sys(hbf + ((size_t)(m0 + lgrp * 4 + q) << 10) + col,
                       (uint32_t)(uint16_t)f2bf(hn));
        if (t == S_ - 1) out[((size_t)(m0 + lgrp * 4 + q) << 10) + col] = hn;
      }
      wait_vm0();
      if (tid == 0)
        __hip_atomic_fetch_add(flagB, 1u, __ATOMIC_RELAXED, __HIP_MEMORY_SCOPE_AGENT);
    }
  }
}

// ---------------- launch ----------------

extern "C" void kernel_launch(void* const* d_in, const int* in_sizes, int n_in,
                              void* d_out, int out_size, void* d_ws, size_t ws_size,
                              hipStream_t stream) {
  const float* x  = (const float*)d_in[0];
  const float* Wm = (const float*)d_in[1];
  const float* bm = (const float*)d_in[2];
  const float* Wh = (const float*)d_in[3];
  const float* bh = (const float*)d_in[4];
  const float* Wz = (const float*)d_in[5];
  const float* bz = (const float*)d_in[6];
  const float* Wr = (const float*)d_in[7];
  const float* br = (const float*)d_in[8];
  const float* Wi = (const float*)d_in[9];
  const float* bi = (const float*)d_in[10];

  char* ws = (char*)d_ws;
  size_t off = 0;
  auto alloc = [&](size_t bytes) -> void* {
    void* p = ws + off; off += (bytes + 255) & ~(size_t)255; return p;
  };
  short* xbf   = (short*)alloc((size_t)B_ * S_ * D_ * 2);
  short* Gcat  = (short*)alloc((size_t)B_ * S_ * 3072 * 2);
  short* Mcat  = (short*)alloc((size_t)3072 * 768 * 2);
  short* Wcat  = (short*)alloc((size_t)3072 * 1024 * 2);
  short* WmT   = (short*)alloc((size_t)768 * 1024 * 2);
  short* Whbf  = (short*)alloc((size_t)1024 * 768 * 2);
  short* pk    = (short*)alloc((size_t)3 * 1024 * 1024 * 2);   // packed r,z,i frags
  float* ccat  = (float*)alloc(3072 * 4);
  float* hf    = (float*)alloc(65536 * 4);
  short* hbf   = (short*)alloc(65536 * 2);
  short* rhbf  = (short*)alloc(65536 * 2);
  uint32_t* flags = (uint32_t*)alloc(4 * 32 * 4);
  if (off > ws_size) return;

  hipMemsetAsync(flags, 0, 4 * 32 * 4, stream);
  cast_f32_bf16_kernel<<<2048, 256, 0, stream>>>(x, xbf, (B_ * S_ * D_) / 8);
  cast_f32_bf16_kernel<<<384, 256, 0, stream>>>(Wh, Whbf, (1024 * 768) / 8);
  build_wcat_kernel<<<1536, 256, 0, stream>>>(Wz, Wr, Wi, Wcat);
  transpose_cast_kernel<<<dim3(24, 32), dim3(32, 8), 0, stream>>>(Wm, WmT);
  ccat_kernel<<<768, 256, 0, stream>>>(Wz, Wr, Wi, bm, bz, br, bi, ccat);
  pack_w_kernel<<<1536, 256, 0, stream>>>(Wz, Wr, Wi, pk);

  // Mcat[3072,768] = Wcat[3072,1024] @ WmT[768,1024]^T
  gemm_nt_kernel<false><<<dim3(24, 6), 256, 0, stream>>>(Wcat, 1024, WmT, Mcat, 768,
                                                         nullptr, 3072, 768, 1024);
  // Gcat[32768,3072] = xbf[32768,768] @ Mcat[3072,768]^T + ccat
  gemm_nt_kernel<false><<<dim3(256, 24), 256, 0, stream>>>(xbf, 768, Mcat, Gcat, 3072,
                                                           ccat, 32768, 3072, 768);
  // hf[64,1024] = x[:,0,:] @ Whbf[1024,768]^T + bh
  gemm_nt_kernel<true><<<dim3(1, 8), 256, 0, stream>>>(xbf, (long)S_ * D_, Whbf, hf, 1024,
                                                       bh, 64, 1024, 768);
  cast_f32_bf16_kernel<<<32, 256, 0, stream>>>(hf, hbf, 65536 / 8);

  recurrence_kernel<<<256, 256, 0, stream>>>(pk, Gcat, hf, hbf, rhbf, flags,
                                             (float*)d_out);
}

// Round 3
// 7036.947 us; speedup vs baseline: 2.1490x; 1.0273x over previous
//
#include <hip/hip_runtime.h>
#include <hip/hip_bf16.h>
#include <stdint.h>

// GRU-style recurrence, B=64 S=512 D=768 H=1024.
//  prep:  cast x->bf16; Wcat_u bf16 [3072,1024]; WmT bf16; Wh bf16; ccat = W*_u@bm + b*;
//         pack recurrent weights (W*[:,1024:]) into per-block MFMA B-fragments (r,z,i).
//  fold:  Mcat[3072,768] = Wcat_u @ WmT^T           (NT bf16 MFMA GEMM)
//  big:   Gcat[32768,3072] = xbf @ Mcat^T + ccat    (NT bf16 MFMA GEMM, bf16 out)
//  h0:    hf[64,1024] = x[:,0,:] @ Whbf^T + bh
//  rec:   persistent, 256 blocks = 4 groups(16 rows) x 64 col-blocks(16 cols each).
//         Sync v3: per-block flag WORDS (no atomics/RMW), sc0sc1 release-store after
//         vmcnt(0) data drain; single designated WAVE polls the 64-flag array with a
//         coalesced 64-lane load + __all + s_sleep backoff; pollers alternate waves
//         so polling overlaps wave0's epilogue. All cross-block data via sc0 sc1.

#define B_  64
#define S_  512
#define D_  768
#define H_  1024

typedef __attribute__((ext_vector_type(8))) short short8;
typedef __attribute__((ext_vector_type(4))) float f32x4;

static __device__ __forceinline__ short f2bf(float f) {
  union { float f; uint32_t u; } v; v.f = f;
  uint32_t u = v.u;
  u += 0x7FFFu + ((u >> 16) & 1u);   // RNE
  return (short)(u >> 16);
}
static __device__ __forceinline__ float bf2f(short s) {
  union { uint32_t u; float f; } v; v.u = ((uint32_t)(uint16_t)s) << 16;
  return v.f;
}
static __device__ __forceinline__ void load_lds16(const void* g, void* l) {
  __builtin_amdgcn_global_load_lds((const __attribute__((address_space(1))) void*)g,
                                   (__attribute__((address_space(3))) void*)l, 16, 0, 0);
}

// ---- fine-grained coherent (cross-XCD) accesses: sc0 sc1 = serialize at L3 ----
static __device__ __forceinline__ short8 load_frag_sys(const short* p) {
  short8 v;
  asm volatile("global_load_dwordx4 %0, %1, off sc0 sc1" : "=v"(v) : "v"(p));
  return v;
}
static __device__ __forceinline__ void store_bf16_sys(short* p, uint32_t v) {
  asm volatile("global_store_short %0, %1, off sc0 sc1" :: "v"(p), "v"(v) : "memory");
}
static __device__ __forceinline__ void store_flag(uint32_t* p, uint32_t v) {
  asm volatile("global_store_dword %0, %1, off sc0 sc1" :: "v"(p), "v"(v) : "memory");
}
static __device__ __forceinline__ void wait_vm0() {
  asm volatile("s_waitcnt vmcnt(0)" ::: "memory");
  __builtin_amdgcn_sched_barrier(0);   // rule 18: keep consumers below the drain
}
// one WAVE polls 64 per-block flags (coalesced 64-lane dword load), no RMW anywhere
static __device__ __forceinline__ void poll_group(const uint32_t* flags64, uint32_t target) {
  const uint32_t* addr = flags64 + (threadIdx.x & 63);
  for (;;) {
    uint32_t v;
    asm volatile("global_load_dword %0, %1, off sc0 sc1\n\ts_waitcnt vmcnt(0)"
                 : "=v"(v) : "v"(addr) : "memory");
    if (__all((int)(v >= target))) break;
    __builtin_amdgcn_s_sleep(1);
  }
  __builtin_amdgcn_sched_barrier(0);
}

// ---------------- prep kernels ----------------

__global__ void cast_f32_bf16_kernel(const float* __restrict__ in, short* __restrict__ out, int n8) {
  int i = blockIdx.x * blockDim.x + threadIdx.x;
  int stride = gridDim.x * blockDim.x;
  for (; i < n8; i += stride) {
    const f32x4* p = (const f32x4*)(in + (size_t)i * 8);
    f32x4 a = p[0], b = p[1];
    short8 o;
    o[0] = f2bf(a[0]); o[1] = f2bf(a[1]); o[2] = f2bf(a[2]); o[3] = f2bf(a[3]);
    o[4] = f2bf(b[0]); o[5] = f2bf(b[1]); o[6] = f2bf(b[2]); o[7] = f2bf(b[3]);
    *(short8*)(out + (size_t)i * 8) = o;
  }
}

// Wcat_u bf16 [3072][1024]: rows 0..1023 = Wz[:, :1024], then Wr, then Wi
__global__ void build_wcat_kernel(const float* __restrict__ Wz, const float* __restrict__ Wr,
                                  const float* __restrict__ Wi, short* __restrict__ out) {
  int idx = blockIdx.x * blockDim.x + threadIdx.x;   // 3072*128
  int n = idx >> 7;
  int k8 = (idx & 127) << 3;
  const float* src;
  if (n < 1024)       src = Wz + ((size_t)n << 11);
  else if (n < 2048)  src = Wr + ((size_t)(n - 1024) << 11);
  else                src = Wi + ((size_t)(n - 2048) << 11);
  const f32x4* p = (const f32x4*)(src + k8);
  f32x4 a = p[0], b = p[1];
  short8 o;
  o[0] = f2bf(a[0]); o[1] = f2bf(a[1]); o[2] = f2bf(a[2]); o[3] = f2bf(a[3]);
  o[4] = f2bf(b[0]); o[5] = f2bf(b[1]); o[6] = f2bf(b[2]); o[7] = f2bf(b[3]);
  *(short8*)(out + ((size_t)n << 10) + k8) = o;
}

// WmT bf16 [768][1024], WmT[d][u] = Wm[u][d]
__global__ void transpose_cast_kernel(const float* __restrict__ in, short* __restrict__ out) {
  __shared__ float tile[32][33];
  int x = (blockIdx.x << 5) + threadIdx.x;    // d, grid.x = 24
  int y0 = (blockIdx.y << 5);                 // u, grid.y = 32
#pragma unroll
  for (int i = threadIdx.y; i < 32; i += 8)
    tile[i][threadIdx.x] = in[(size_t)(y0 + i) * 768 + x];
  __syncthreads();
  int ox = (blockIdx.y << 5) + threadIdx.x;
  int oy0 = (blockIdx.x << 5);
#pragma unroll
  for (int i = threadIdx.y; i < 32; i += 8)
    out[(size_t)(oy0 + i) * 1024 + ox] = f2bf(tile[threadIdx.x][i]);
}

// ccat[n] = sum_k W*[n_local, k<1024] * bm[k] + b*[n_local]
__global__ void ccat_kernel(const float* __restrict__ Wz, const float* __restrict__ Wr,
                            const float* __restrict__ Wi, const float* __restrict__ bm,
                            const float* __restrict__ bz, const float* __restrict__ br,
                            const float* __restrict__ bi, float* __restrict__ ccat) {
  int w = (blockIdx.x * blockDim.x + threadIdx.x) >> 6;
  int lane = threadIdx.x & 63;
  if (w >= 3072) return;
  const float* src; const float* bsrc; int ln;
  if (w < 1024)      { src = Wz + ((size_t)w << 11);          bsrc = bz; ln = w; }
  else if (w < 2048) { src = Wr + ((size_t)(w - 1024) << 11); bsrc = br; ln = w - 1024; }
  else               { src = Wi + ((size_t)(w - 2048) << 11); bsrc = bi; ln = w - 2048; }
  float acc = 0.f;
  for (int k = lane; k < 1024; k += 64) acc += src[k] * bm[k];
  for (int off = 32; off > 0; off >>= 1) acc += __shfl_down(acc, off, 64);
  if (lane == 0) ccat[w] = acc + bsrc[ln];
}

// pack recurrent weights: idx = (((m*64 + j)*4 + w)*8 + t8)*64 + lane, m: 0=r 1=z 2=i
// value = W_m[16j + (lane&15)][1024 + 256w + 32*t8 + 8*(lane>>4) + e]
__global__ void pack_w_kernel(const float* __restrict__ Wz, const float* __restrict__ Wr,
                              const float* __restrict__ Wi, short* __restrict__ out) {
  int idx = blockIdx.x * blockDim.x + threadIdx.x;   // 393216
  int lane = idx & 63;
  int t8 = (idx >> 6) & 7;
  int w = (idx >> 9) & 3;
  int j = (idx >> 11) & 63;
  int m = idx >> 17;
  int colv = (j << 4) + (lane & 15);
  int k = 1024 + (w << 8) + (t8 << 5) + ((lane >> 4) << 3);
  const float* W = (m == 0) ? Wr : (m == 1) ? Wz : Wi;
  const float* p = W + ((size_t)colv << 11) + k;
  short8 o;
#pragma unroll
  for (int e = 0; e < 8; ++e) o[e] = f2bf(p[e]);
  *(short8*)(out + ((size_t)idx << 3)) = o;
}

// ---------------- NT bf16 MFMA GEMM: C[M,N] = A[M,K] @ Bm[N,K]^T (+bias[col]) ----------------

template<bool OUT_F32>
__launch_bounds__(256, 2)
__global__ void gemm_nt_kernel(const short* __restrict__ A, long lda,
                               const short* __restrict__ Bm,
                               void* __restrict__ Cv, int ldc,
                               const float* __restrict__ bias,
                               int M, int N, int K) {
  __shared__ short ldsA[128 * 64];
  __shared__ short ldsB[128 * 64];
  const int tile_m = blockIdx.x << 7;
  const int tile_n = blockIdx.y << 7;
  const int tid = threadIdx.x;
  const int wave = tid >> 6;
  const int lane = tid & 63;
  const int wm = wave & 1;
  const int wn = wave >> 1;
  const int lrow = lane & 15;
  const int lgrp = lane >> 4;

  f32x4 acc[4][4];
#pragma unroll
  for (int a = 0; a < 4; ++a)
#pragma unroll
    for (int b = 0; b < 4; ++b) acc[a][b] = (f32x4){0.f, 0.f, 0.f, 0.f};

  for (int kt = 0; kt < K; kt += 64) {
    __syncthreads();
#pragma unroll
    for (int c = 0; c < 4; ++c) {
      int o = ((wave * 4 + c) << 10) + (lane << 4);
      int row = o >> 7;
      int cb = (o & 127) ^ ((row & 7) << 4);   // pre-swizzled source (rule 21)
      int grow = tile_m + row; if (grow >= M) grow = M - 1;
      load_lds16(A + (size_t)grow * lda + kt + (cb >> 1),
                 (char*)ldsA + ((wave * 4 + c) << 10));
      int gcol = tile_n + row;
      load_lds16(Bm + (size_t)gcol * K + kt + (cb >> 1),
                 (char*)ldsB + ((wave * 4 + c) << 10));
    }
    __syncthreads();
#pragma unroll
    for (int kk = 0; kk < 2; ++kk) {
      short8 af[4], bfr[4];
      int kb = (kk << 6) + (lgrp << 4);
#pragma unroll
      for (int a = 0; a < 4; ++a) {
        int r = (wm << 6) + (a << 4) + lrow;
        af[a] = *(const short8*)((const char*)ldsA + (r << 7) + (kb ^ ((r & 7) << 4)));
        int rn = (wn << 6) + (a << 4) + lrow;
        bfr[a] = *(const short8*)((const char*)ldsB + (rn << 7) + (kb ^ ((rn & 7) << 4)));
      }
#pragma unroll
      for (int a = 0; a < 4; ++a)
#pragma unroll
        for (int b = 0; b < 4; ++b)
          acc[a][b] = __builtin_amdgcn_mfma_f32_16x16x32_bf16(af[a], bfr[b], acc[a][b], 0, 0, 0);
    }
  }
#pragma unroll
  for (int a = 0; a < 4; ++a)
#pragma unroll
    for (int b = 0; b < 4; ++b)
#pragma unroll
      for (int q = 0; q < 4; ++q) {
        int r = tile_m + (wm << 6) + (a << 4) + lgrp * 4 + q;   // m89 C layout
        int cc = tile_n + (wn << 6) + (b << 4) + lrow;
        if (r < M) {
          float v = acc[a][b][q];
          if (bias) v += bias[cc];
          if (OUT_F32) ((float*)Cv)[(size_t)r * ldc + cc] = v;
          else         ((short*)Cv)[(size_t)r * ldc + cc] = f2bf(v);
        }
      }
}

// ---------------- persistent recurrence ----------------
// 256 blocks: g = blk>>6 (16 batch rows), j = blk&63 (cols 16j..16j+16 of ALL gates).
// flags layout: flags + g*128 : [0..63] = flagA (phase1 done), [64..127] = flagB.
// Pollers: wave2 polls flagB (phase-1 gate), wave1 polls flagA (phase-2 gate);
// wave0 does epilogues — poll overlaps epilogue+release of the neighbor phase.

__launch_bounds__(256, 1)
__global__ void recurrence_kernel(const short* __restrict__ pk,
                                  const short* __restrict__ Gcat,
                                  const float* __restrict__ hf,
                                  short* __restrict__ hbf,
                                  short* __restrict__ rhbf,
                                  uint32_t* __restrict__ flags,
                                  float* __restrict__ out) {
  __shared__ float red[3][3][256];    // [matrix r/z/i][wave-1][lane*4+q]
  const int blk = blockIdx.x;
  const int g = blk >> 6;
  const int j = blk & 63;
  const int tid = threadIdx.x;
  const int wave = tid >> 6;
  const int lane = tid & 63;
  const int lrow = lane & 15;
  const int lgrp = lane >> 4;
  const int m0 = g << 4;

  // resident weights: per wave k-quarter, 8 frags per matrix
  short8 wr[8], wz[8], wi[8];
  {
    const short8* p8 = (const short8*)pk;
    size_t base = ((size_t)j * 4 + wave) * 8;
#pragma unroll
    for (int t8 = 0; t8 < 8; ++t8) wr[t8] = p8[(base + t8) * 64 + lane];
#pragma unroll
    for (int t8 = 0; t8 < 8; ++t8) wz[t8] = p8[((size_t)2048 + base + t8) * 64 + lane];
#pragma unroll
    for (int t8 = 0; t8 < 8; ++t8) wi[t8] = p8[((size_t)4096 + base + t8) * 64 + lane];
  }

  uint32_t* flagA = flags + g * 128;
  uint32_t* flagB = flags + g * 128 + 64;

  const int col = (j << 4) + lrow;                   // C column (0..1023)
  float hold[4];
  if (wave == 0) {
#pragma unroll
    for (int q = 0; q < 4; ++q)
      hold[q] = hf[((size_t)(m0 + lgrp * 4 + q) << 10) + col];
  }

  const short* hrow  = hbf  + ((size_t)(m0 + lrow) << 10);   // A row = lane&15
  const short* rhrow = rhbf + ((size_t)(m0 + lrow) << 10);
  const int kq = wave << 8;

  for (int t = 0; t < S_; ++t) {
    // prefetch Gcat precomputed gate inputs (normal cached loads; overlap poll/barrier)
    float gr[4], gz[4], gi[4];
    if (wave == 0) {
#pragma unroll
      for (int q = 0; q < 4; ++q) {
        size_t rbase = ((size_t)(m0 + lgrp * 4 + q) * S_ + t) * 3072;
        gz[q] = bf2f(Gcat[rbase + col]);
        gr[q] = bf2f(Gcat[rbase + 1024 + col]);
        gi[q] = bf2f(Gcat[rbase + 2048 + col]);
      }
    }
    // ---- phase 1 gate: all blocks finished phase2 of t-1 ----
    if (t > 0 && wave == 2) poll_group(flagB, (uint32_t)t);
    __syncthreads();                                  // B1
    short8 hfrag[8];
#pragma unroll
    for (int t8 = 0; t8 < 8; ++t8)
      hfrag[t8] = load_frag_sys(hrow + kq + (t8 << 5) + (lgrp << 3));
    wait_vm0();
    f32x4 accr = (f32x4){0.f,0.f,0.f,0.f}, accz = (f32x4){0.f,0.f,0.f,0.f};
#pragma unroll
    for (int t8 = 0; t8 < 8; ++t8) {
      accr = __builtin_amdgcn_mfma_f32_16x16x32_bf16(hfrag[t8], wr[t8], accr, 0, 0, 0);
      accz = __builtin_amdgcn_mfma_f32_16x16x32_bf16(hfrag[t8], wz[t8], accz, 0, 0, 0);
    }
    if (wave != 0) {
#pragma unroll
      for (int q = 0; q < 4; ++q) {
        red[0][wave - 1][lane * 4 + q] = accr[q];
        red[1][wave - 1][lane * 4 + q] = accz[q];
      }
    }
    __syncthreads();                                  // B2
    f32x4 zt = (f32x4){0.f,0.f,0.f,0.f};
    if (wave == 0) {
#pragma unroll
      for (int q = 0; q < 4; ++q) {
        int li = lane * 4 + q;
        float sr = accr[q] + red[0][0][li] + red[0][1][li] + red[0][2][li] + gr[q];
        float sz = accz[q] + red[1][0][li] + red[1][1][li] + red[1][2][li] + gz[q];
        sr = fminf(fmaxf(sr, -30.f), 30.f);
        sz = fminf(fmaxf(sz, -30.f), 30.f);
        float rv = 1.f / (1.f + __expf(-sr));
        zt[q] = 1.f / (1.f + __expf(-sz));
        store_bf16_sys(rhbf + ((size_t)(m0 + lgrp * 4 + q) << 10) + col,
                       (uint32_t)(uint16_t)f2bf(rv * hold[q]));
      }
      wait_vm0();                                     // release: data acked at L3
      if (lane == 0) store_flag(flagA + j, (uint32_t)(t + 1));
    }
    // ---- phase 2 gate: all blocks finished phase1 of t (overlaps wave0 epilogue) ----
    if (wave == 1) poll_group(flagA, (uint32_t)(t + 1));
    __syncthreads();                                  // B3
    short8 rhfrag[8];
#pragma unroll
    for (int t8 = 0; t8 < 8; ++t8)
      rhfrag[t8] = load_frag_sys(rhrow + kq + (t8 << 5) + (lgrp << 3));
    wait_vm0();
    f32x4 acci = (f32x4){0.f,0.f,0.f,0.f};
#pragma unroll
    for (int t8 = 0; t8 < 8; ++t8)
      acci = __builtin_amdgcn_mfma_f32_16x16x32_bf16(rhfrag[t8], wi[t8], acci, 0, 0, 0);
    if (wave != 0) {
#pragma unroll
      for (int q = 0; q < 4; ++q) red[2][wave - 1][lane * 4 + q] = acci[q];
    }
    __syncthreads();                                  // B4
    if (wave == 0) {
#pragma unroll
      for (int q = 0; q < 4; ++q) {
        int li = lane * 4 + q;
        float si = acci[q] + red[2][0][li] + red[2][1][li] + red[2][2][li] + gi[q];
        si = fminf(fmaxf(si, -30.f), 30.f);
        float e2 = __expf(2.f * si);
        float hp = (e2 - 1.f) / (e2 + 1.f);
        float hn = (1.f - zt[q]) * hold[q] + zt[q] * hp;
        hold[q] = hn;
        store_bf16_sys(hbf + ((size_t)(m0 + lgrp * 4 + q) << 10) + col,
                       (uint32_t)(uint16_t)f2bf(hn));
        if (t == S_ - 1) out[((size_t)(m0 + lgrp * 4 + q) << 10) + col] = hn;
      }
      wait_vm0();                                     // release
      if (lane == 0) store_flag(flagB + j, (uint32_t)(t + 1));
    }
    // next-iteration phase-1 poll (wave2) overlaps this epilogue; B1 re-converges.
  }
}

// ---------------- launch ----------------

extern "C" void kernel_launch(void* const* d_in, const int* in_sizes, int n_in,
                              void* d_out, int out_size, void* d_ws, size_t ws_size,
                              hipStream_t stream) {
  const float* x  = (const float*)d_in[0];
  const float* Wm = (const float*)d_in[1];
  const float* bm = (const float*)d_in[2];
  const float* Wh = (const float*)d_in[3];
  const float* bh = (const float*)d_in[4];
  const float* Wz = (const float*)d_in[5];
  const float* bz = (const float*)d_in[6];
  const float* Wr = (const float*)d_in[7];
  const float* br = (const float*)d_in[8];
  const float* Wi = (const float*)d_in[9];
  const float* bi = (const float*)d_in[10];

  char* ws = (char*)d_ws;
  size_t off = 0;
  auto alloc = [&](size_t bytes) -> void* {
    void* p = ws + off; off += (bytes + 255) & ~(size_t)255; return p;
  };
  short* xbf   = (short*)alloc((size_t)B_ * S_ * D_ * 2);
  short* Gcat  = (short*)alloc((size_t)B_ * S_ * 3072 * 2);
  short* Mcat  = (short*)alloc((size_t)3072 * 768 * 2);
  short* Wcat  = (short*)alloc((size_t)3072 * 1024 * 2);
  short* WmT   = (short*)alloc((size_t)768 * 1024 * 2);
  short* Whbf  = (short*)alloc((size_t)1024 * 768 * 2);
  short* pk    = (short*)alloc((size_t)3 * 1024 * 1024 * 2);   // packed r,z,i frags
  float* ccat  = (float*)alloc(3072 * 4);
  float* hf    = (float*)alloc(65536 * 4);
  short* hbf   = (short*)alloc(65536 * 2);
  short* rhbf  = (short*)alloc(65536 * 2);
  uint32_t* flags = (uint32_t*)alloc(4 * 128 * 4);
  if (off > ws_size) return;

  hipMemsetAsync(flags, 0, 4 * 128 * 4, stream);
  cast_f32_bf16_kernel<<<2048, 256, 0, stream>>>(x, xbf, (B_ * S_ * D_) / 8);
  cast_f32_bf16_kernel<<<384, 256, 0, stream>>>(Wh, Whbf, (1024 * 768) / 8);
  build_wcat_kernel<<<1536, 256, 0, stream>>>(Wz, Wr, Wi, Wcat);
  transpose_cast_kernel<<<dim3(24, 32), dim3(32, 8), 0, stream>>>(Wm, WmT);
  ccat_kernel<<<768, 256, 0, stream>>>(Wz, Wr, Wi, bm, bz, br, bi, ccat);
  pack_w_kernel<<<1536, 256, 0, stream>>>(Wz, Wr, Wi, pk);

  // Mcat[3072,768] = Wcat[3072,1024] @ WmT[768,1024]^T
  gemm_nt_kernel<false><<<dim3(24, 6), 256, 0, stream>>>(Wcat, 1024, WmT, Mcat, 768,
                                                         nullptr, 3072, 768, 1024);
  // Gcat[32768,3072] = xbf[32768,768] @ Mcat[3072,768]^T + ccat
  gemm_nt_kernel<false><<<dim3(256, 24), 256, 0, stream>>>(xbf, 768, Mcat, Gcat, 3072,
                                                           ccat, 32768, 3072, 768);
  // hf[64,1024] = x[:,0,:] @ Whbf[1024,768]^T + bh
  gemm_nt_kernel<true><<<dim3(1, 8), 256, 0, stream>>>(xbf, (long)S_ * D_, Whbf, hf, 1024,
                                                       bh, 64, 1024, 768);
  cast_f32_bf16_kernel<<<32, 256, 0, stream>>>(hf, hbf, 65536 / 8);

  recurrence_kernel<<<256, 256, 0, stream>>>(pk, Gcat, hf, hbf, rhbf, flags,
                                             (float*)d_out);
}